// Round 1
// baseline (5499.101 us; speedup 1.0000x reference)
//
#include <hip/hip_runtime.h>
#include <hip/hip_bf16.h>
#include <stdint.h>

// ---------------------------------------------------------------------------
// BasisCustBiLSTM: per-sample basis-mixed BiLSTM.
// Strategy:
//   k_meta   : c_batch (MLP+softmax) + lengths (robust mask dtype detection)
//   k_xbf    : x -> bf16
//   k_whhp   : basis Whh -> bf16 MFMA-B-fragment layout (register-resident later)
//   k_bias   : mixed biases
//   k_mixwih : per-sample mixed Wih (bf16), one direction at a time (ws reuse)
//   k_gemm   : xproj[dir,b,t,g] = x[b,t,:] @ Wih_mix[dir,b]^T   (MFMA 128x128)
//   k_recur  : persistent 256-block kernel; 128 WGs/direction; basis Whh in
//              VGPRs; per step: MFMA -> c-mix -> LDS reduce -> LSTM cell ->
//              global h broadcast + device-scope spin barrier.
// ---------------------------------------------------------------------------

typedef __attribute__((ext_vector_type(8))) __bf16 bf16x8;
typedef __attribute__((ext_vector_type(4))) __bf16 bf16x4;
typedef __attribute__((ext_vector_type(4))) float  f32x4;

#define TT 256
#define BBATCH 32

__device__ __forceinline__ __bf16 f2bf(float f){
  unsigned u = __builtin_bit_cast(unsigned, f);
  unsigned short r = (unsigned short)((u + 0x7fffu + ((u >> 16) & 1u)) >> 16);
  return __builtin_bit_cast(__bf16, r);
}
__device__ __forceinline__ float sigm(float x){
  x = fminf(fmaxf(x, -30.f), 30.f);
  return 1.f / (1.f + __expf(-x));
}
__device__ __forceinline__ float tanh_(float x){
  x = fminf(fmaxf(x, -15.f), 15.f);
  float e = __expf(2.f * x);
  return (e - 1.f) / (e + 1.f);
}

// ---------------------------------------------------------------------------
// k_meta: lengths from mask (dtype-robust) + c_batch MLP/softmax. One block.
// ---------------------------------------------------------------------------
__global__ void k_meta(const void* __restrict__ mask,
                       const int* __restrict__ meta_a, const int* __restrict__ meta_c,
                       const float* __restrict__ emb_a, const float* __restrict__ emb_c,
                       const float* __restrict__ W1, const float* __restrict__ b1,
                       const float* __restrict__ W2,
                       float* __restrict__ c_out, int* __restrict__ len_out)
{
  __shared__ int s_bad;
  __shared__ float q_sh[32][128];
  __shared__ float hid[32][64];
  const int tid = threadIdx.x;
  if (tid == 0) s_bad = 0;
  __syncthreads();

  // lengths assuming uint8 bool mask; validate structure (prefix of ones).
  if (tid < 32){
    const unsigned char* m8 = (const unsigned char*)mask;
    int cnt = 0, seen0 = 0, bad = 0;
    for (int t = 0; t < TT; ++t){
      unsigned char v = m8[tid * TT + t];
      if (v > 1) bad = 1;
      if (v){ if (seen0) bad = 1; cnt++; } else seen0 = 1;
    }
    if (tid == 0 && cnt != TT) bad = 1;   // row 0 has length exactly T
    if (bad) atomicAdd(&s_bad, 1);
    len_out[tid] = cnt;
  }
  // stage query = concat(emb_author, emb_century)
  {
    int b = tid >> 3, p = tid & 7;
    int a = meta_a[b], c = meta_c[b];
    for (int i = 0; i < 16; ++i){
      int qi = p * 16 + i;
      q_sh[b][qi] = (qi < 64) ? emb_a[a * 64 + qi] : emb_c[c * 64 + (qi - 64)];
    }
  }
  __syncthreads();
  if (s_bad){            // mask was really int32 (buffer is 32KB, safe to read)
    if (tid < 32){
      const int* m32 = (const int*)mask;
      int cnt = 0;
      for (int t = 0; t < TT; ++t) if (m32[tid * TT + t]) cnt++;
      len_out[tid] = cnt;
    }
  }
  // hidden = tanh(q @ W1 + b1): thread (b, kgroup of 8)
  {
    int b = tid >> 3, kg = tid & 7;
    for (int k8 = 0; k8 < 8; ++k8){
      int k = kg * 8 + k8;
      float s = b1[k];
      for (int i = 0; i < 128; ++i) s += q_sh[b][i] * W1[i * 64 + k];
      hid[b][k] = tanhf(s);
    }
  }
  __syncthreads();
  if (tid < 32){
    float lg[8]; float mx = -1e30f;
    for (int n = 0; n < 8; ++n){
      float s = 0.f;
      for (int k = 0; k < 64; ++k) s += hid[tid][k] * W2[k * 8 + n];
      lg[n] = s; mx = fmaxf(mx, s);
    }
    float den = 0.f;
    for (int n = 0; n < 8; ++n){ lg[n] = expf(lg[n] - mx); den += lg[n]; }
    for (int n = 0; n < 8; ++n) c_out[tid * 8 + n] = lg[n] / den;
  }
}

// ---------------------------------------------------------------------------
// k_xbf: x (f32) -> bf16, 8 elems/thread
// ---------------------------------------------------------------------------
__global__ void k_xbf(const float* __restrict__ x, __bf16* __restrict__ xb)
{
  int i = blockIdx.x * 256 + threadIdx.x;       // 524288 threads
  if (i >= 524288) return;
  f32x4 a = *(const f32x4*)(x + (size_t)i * 8);
  f32x4 b = *(const f32x4*)(x + (size_t)i * 8 + 4);
  bf16x8 o;
  #pragma unroll
  for (int j = 0; j < 4; ++j){ o[j] = f2bf(a[j]); o[4 + j] = f2bf(b[j]); }
  *(bf16x8*)(xb + (size_t)i * 8) = o;
}

// ---------------------------------------------------------------------------
// k_whhp: basis Whh -> bf16 B-fragment layout.
// out element group idx = ((((dir*128+wg)*4 + wave)*4 + kt)*8 + n)*64 + lane,
// 8 bf16 per group: W_hh[n][g(col)][k..k+7],
//   col = lane&15 -> gate=col>>2, jj=col&3, g = gate*512 + wg*4 + jj
//   k = (wave*4+kt)*32 + (lane>>4)*8
// ---------------------------------------------------------------------------
__global__ void k_whhp(const float* __restrict__ whh_f, const float* __restrict__ whh_r,
                       __bf16* __restrict__ outp)
{
  int idx = blockIdx.x * 256 + threadIdx.x;     // 0..2097151
  int lane = idx & 63; int grp = idx >> 6;
  int n  = grp & 7;  grp >>= 3;
  int kt = grp & 3;  grp >>= 2;
  int wv = grp & 3;  grp >>= 2;
  int wg = grp & 127; int dir = (grp >> 7) & 1;
  int col = lane & 15, quad = lane >> 4;
  int gate = col >> 2, jj = col & 3;
  int g = gate * 512 + wg * 4 + jj;
  int k = (wv * 4 + kt) * 32 + quad * 8;
  const float* Wb = dir ? whh_r : whh_f;
  const float* s = Wb + ((size_t)n * 2048 + g) * 512 + k;
  f32x4 a = *(const f32x4*)s, b = *(const f32x4*)(s + 4);
  bf16x8 o;
  #pragma unroll
  for (int j = 0; j < 4; ++j){ o[j] = f2bf(a[j]); o[4 + j] = f2bf(b[j]); }
  *(bf16x8*)(outp + (size_t)idx * 8) = o;
}

// ---------------------------------------------------------------------------
// k_bias: bias_mix[dir][b][g] = sum_n c[b,n]*bias_basis[dir][n][g]
// ---------------------------------------------------------------------------
__global__ void k_bias(const float* __restrict__ b_f, const float* __restrict__ b_r,
                       const float* __restrict__ cb, float* __restrict__ bm)
{
  int idx = blockIdx.x * 256 + threadIdx.x;     // 0..131071
  int dir = idx >> 16; int b = (idx >> 11) & 31; int g = idx & 2047;
  const float* bb = dir ? b_r : b_f;
  float s = 0.f;
  #pragma unroll
  for (int n = 0; n < 8; ++n) s += cb[b * 8 + n] * bb[n * 2048 + g];
  bm[idx] = s;
}

// ---------------------------------------------------------------------------
// k_mixwih: Wih_mix[b][g][k] (bf16) = sum_n c[b,n] * Wb[n][g][k], one dir.
// Thread owns (g, k8): holds 8 basis x 8 k values in regs, loops over b.
// ---------------------------------------------------------------------------
__global__ void k_mixwih(const float* __restrict__ Wb, const float* __restrict__ cb,
                         __bf16* __restrict__ wmix)
{
  __shared__ float cs[256];
  int tid = threadIdx.x;
  cs[tid] = cb[tid];
  __syncthreads();
  int idx = blockIdx.x * 256 + tid;             // 0..131071: g*64 + k8
  int g = idx >> 6, k8 = idx & 63;
  float src[8][8];
  #pragma unroll
  for (int n = 0; n < 8; ++n){
    const float* p = Wb + ((size_t)n * 2048 + g) * 512 + k8 * 8;
    f32x4 lo = *(const f32x4*)p, hi = *(const f32x4*)(p + 4);
    #pragma unroll
    for (int j = 0; j < 4; ++j){ src[n][j] = lo[j]; src[n][4 + j] = hi[j]; }
  }
  for (int b = 0; b < 32; ++b){
    float acc[8] = {0,0,0,0,0,0,0,0};
    #pragma unroll
    for (int n = 0; n < 8; ++n){
      float cn = cs[b * 8 + n];
      #pragma unroll
      for (int j = 0; j < 8; ++j) acc[j] += cn * src[n][j];
    }
    bf16x8 o;
    #pragma unroll
    for (int j = 0; j < 8; ++j) o[j] = f2bf(acc[j]);
    *(bf16x8*)(wmix + ((size_t)b * 2048 + g) * 512 + k8 * 8) = o;
  }
}

// ---------------------------------------------------------------------------
// k_gemm: xproj[b][t][g] = x_bf16[b][t][:] @ Wih_mix[b][g][:]   (one dir)
// 128x128 tile, BK=64, 4 waves in 2x2 of 64x64, padded LDS (72) for 2-way banks.
// grid = 32 samples * (2 m-tiles * 16 n-tiles) = 1024 blocks
// ---------------------------------------------------------------------------
__global__ __launch_bounds__(256) void k_gemm(const __bf16* __restrict__ xb,
                                              const __bf16* __restrict__ wmix,
                                              float* __restrict__ xp)
{
  __shared__ __bf16 As[128][72];
  __shared__ __bf16 Bs[128][72];
  const int tid = threadIdx.x, lane = tid & 63, wv = tid >> 6;
  const int quad = lane >> 4, c16 = lane & 15;
  const int wm_ = wv >> 1, wn_ = wv & 1;
  const int b = blockIdx.x >> 5, tile = blockIdx.x & 31;
  const int m0 = (tile >> 4) * 128, n0 = (tile & 15) * 128;
  const __bf16* Ap = xb + (size_t)b * TT * 512;
  const __bf16* Bp = wmix + (size_t)b * 2048 * 512;
  float* Cp = xp + (size_t)b * TT * 2048;

  f32x4 acc[4][4];
  #pragma unroll
  for (int i = 0; i < 4; ++i)
    #pragma unroll
    for (int j = 0; j < 4; ++j) acc[i][j] = (f32x4){0,0,0,0};

  for (int k0 = 0; k0 < 512; k0 += 64){
    __syncthreads();
    #pragma unroll
    for (int it = 0; it < 4; ++it){
      int r = it * 32 + (tid >> 3), c = (tid & 7) * 8;
      *(bf16x8*)&As[r][c] = *(const bf16x8*)(Ap + (size_t)(m0 + r) * 512 + k0 + c);
      *(bf16x8*)&Bs[r][c] = *(const bf16x8*)(Bp + (size_t)(n0 + r) * 512 + k0 + c);
    }
    __syncthreads();
    #pragma unroll
    for (int kt = 0; kt < 2; ++kt){
      bf16x8 af[4], bfr[4];
      #pragma unroll
      for (int i = 0; i < 4; ++i){
        af[i]  = *(const bf16x8*)&As[wm_ * 64 + i * 16 + c16][kt * 32 + quad * 8];
        bfr[i] = *(const bf16x8*)&Bs[wn_ * 64 + i * 16 + c16][kt * 32 + quad * 8];
      }
      #pragma unroll
      for (int i = 0; i < 4; ++i)
        #pragma unroll
        for (int j = 0; j < 4; ++j)
          acc[i][j] = __builtin_amdgcn_mfma_f32_16x16x32_bf16(af[i], bfr[j], acc[i][j], 0, 0, 0);
    }
  }
  #pragma unroll
  for (int i = 0; i < 4; ++i)
    #pragma unroll
    for (int j = 0; j < 4; ++j){
      int colg = n0 + wn_ * 64 + j * 16 + c16;
      #pragma unroll
      for (int r = 0; r < 4; ++r){
        int row = m0 + wm_ * 64 + i * 16 + quad * 4 + r;
        Cp[(size_t)row * 2048 + colg] = acc[i][j][r];
      }
    }
}

// ---------------------------------------------------------------------------
// k_recur: persistent recurrence. 256 blocks (128/dir), 256 threads.
// WG (dir,wg) owns h channels [4wg,4wg+4) = 16 gate columns.
// Basis Whh B-fragments live in VGPRs (32 x 16B per lane).
// Waves split K (128 each); c-mix per wave; cross-wave reduce in LDS.
// ---------------------------------------------------------------------------
__global__ __launch_bounds__(256, 1) void k_recur(
    const __bf16* __restrict__ whhp,
    const float*  __restrict__ xproj,   // [2][32][256][2048]
    const float*  __restrict__ biasm,   // [2][32][2048]
    const float*  __restrict__ cb,      // [32][8]
    const int*    __restrict__ lens,    // [32]
    __bf16* hglob,                      // [2 dir][2 buf][32][512]
    unsigned int* cnt,                  // [2] stride 32
    float* __restrict__ out)            // [32][256][1024]
{
  const int tid = threadIdx.x, lane = tid & 63, wv = tid >> 6;
  const int quad = lane >> 4, c16 = lane & 15;
  const int bid = blockIdx.x, dir = bid >> 7, wg = bid & 127;
  const int hidx0 = wg * 4;

  // basis-weight B fragments -> registers
  bf16x8 bfrag[4][8];
  {
    const __bf16* base = whhp + (size_t)(bid * 4 + wv) * 4 * (8 * 512);
    #pragma unroll
    for (int kt = 0; kt < 4; ++kt)
      #pragma unroll
      for (int n = 0; n < 8; ++n)
        bfrag[kt][n] = *(const bf16x8*)(base + (size_t)(kt * 8 + n) * 512 + lane * 8);
  }
  // c coefficients per accumulator row (rows = quad*4+r of each 16-tile)
  f32x4 ccv[2][8];
  #pragma unroll
  for (int mt = 0; mt < 2; ++mt)
    #pragma unroll
    for (int n = 0; n < 8; ++n){
      f32x4 v;
      #pragma unroll
      for (int r = 0; r < 4; ++r) v[r] = cb[(mt * 16 + quad * 4 + r) * 8 + n];
      ccv[mt][n] = v;
    }

  const int bb_ = tid >> 2, jj_ = tid & 3;   // (sample, h-sub) for tid<128
  float bias_g[4] = {0, 0, 0, 0};
  int mylen = 0;
  float cstate = 0.f;
  if (tid < 128){
    #pragma unroll
    for (int g = 0; g < 4; ++g)
      bias_g[g] = biasm[(size_t)(dir * 32 + bb_) * 2048 + g * 512 + hidx0 + jj_];
    mylen = lens[bb_];
  }

  __shared__ float red[4][2][64][4];
  __shared__ float xg[32][4][4];
  __shared__ float outst[32][4];
  __shared__ __bf16 hbst[32][4];

  // zero our chunk of h buffer 0, then arrive (pre-loop barrier contribution)
  {
    __bf16* hg0 = hglob + (size_t)(dir * 2 + 0) * 32 * 512;
    if (tid < 32){
      bf16x4 z;
      z[0] = z[1] = z[2] = z[3] = __builtin_bit_cast(__bf16, (unsigned short)0);
      *(bf16x4*)(hg0 + (size_t)tid * 512 + hidx0) = z;
    }
  }
  unsigned int* mycnt = cnt + dir * 32;
  if (tid == 0)
    __hip_atomic_fetch_add(mycnt, 1u, __ATOMIC_RELEASE, __HIP_MEMORY_SCOPE_AGENT);

  // prefetch xproj for step 0
  f32x4 pf = {0, 0, 0, 0};
  const int b_pf = tid >> 2, g_pf = tid & 3;
  if (tid < 128){
    int to0 = dir ? (TT - 1) : 0;
    pf = *(const f32x4*)(xproj + ((size_t)(dir * 32 + b_pf) * TT + to0) * 2048
                         + g_pf * 512 + hidx0);
  }

  for (int t = 0; t < TT; ++t){
    const int to = dir ? (TT - 1 - t) : t;
    if (tid == 0){
      unsigned tgt = (unsigned)(t + 1) * 128u;
      while (__hip_atomic_load(mycnt, __ATOMIC_ACQUIRE, __HIP_MEMORY_SCOPE_AGENT) < tgt)
        __builtin_amdgcn_s_sleep(1);
      __threadfence();   // L1/L2 invalidate: h written on other XCDs
    }
    __syncthreads();     // S0

    // A fragments straight from the global h broadcast buffer
    const __bf16* hr = hglob + (size_t)(dir * 2 + (t & 1)) * 32 * 512;
    bf16x8 af[2][4];
    #pragma unroll
    for (int mt = 0; mt < 2; ++mt)
      #pragma unroll
      for (int kt = 0; kt < 4; ++kt)
        af[mt][kt] = *(const bf16x8*)(hr + (size_t)(mt * 16 + c16) * 512
                                      + (wv * 4 + kt) * 32 + quad * 8);

    f32x4 acc[8][2];
    #pragma unroll
    for (int n = 0; n < 8; ++n){ acc[n][0] = (f32x4){0,0,0,0}; acc[n][1] = (f32x4){0,0,0,0}; }
    #pragma unroll
    for (int kt = 0; kt < 4; ++kt)
      #pragma unroll
      for (int n = 0; n < 8; ++n){
        acc[n][0] = __builtin_amdgcn_mfma_f32_16x16x32_bf16(af[0][kt], bfrag[kt][n], acc[n][0], 0, 0, 0);
        acc[n][1] = __builtin_amdgcn_mfma_f32_16x16x32_bf16(af[1][kt], bfrag[kt][n], acc[n][1], 0, 0, 0);
      }
    f32x4 mix0 = {0,0,0,0}, mix1 = {0,0,0,0};
    #pragma unroll
    for (int n = 0; n < 8; ++n){
      mix0 += ccv[0][n] * acc[n][0];
      mix1 += ccv[1][n] * acc[n][1];
    }
    *(f32x4*)&red[wv][0][lane][0] = mix0;
    *(f32x4*)&red[wv][1][lane][0] = mix1;
    if (tid < 128)
      *(f32x4*)&xg[b_pf][g_pf][0] = pf;
    if (t < TT - 1 && tid < 128){
      int ton = dir ? (TT - 2 - t) : (t + 1);
      pf = *(const f32x4*)(xproj + ((size_t)(dir * 32 + b_pf) * TT + ton) * 2048
                           + g_pf * 512 + hidx0);
    }
    __syncthreads();     // S2

    if (tid < 128){
      const int r = bb_ & 15, mt = bb_ >> 4, rg = r & 3, qp = r >> 2;
      float gv[4];
      #pragma unroll
      for (int g = 0; g < 4; ++g){
        int li = qp * 16 + g * 4 + jj_;
        float s = red[0][mt][li][rg] + red[1][mt][li][rg]
                + red[2][mt][li][rg] + red[3][mt][li][rg];
        gv[g] = s + xg[bb_][g][jj_] + bias_g[g];
      }
      float i_ = sigm(gv[0]);
      float f_ = sigm(gv[1]);
      float g_ = tanh_(gv[2]);
      float o_ = sigm(gv[3]);
      bool valid = (to < mylen);
      float cy = valid ? (f_ * cstate + i_ * g_) : 0.f;
      float hy = valid ? (o_ * tanh_(cy)) : 0.f;
      cstate = cy;
      outst[bb_][jj_] = hy;
      hbst[bb_][jj_] = f2bf(hy);
    }
    __syncthreads();     // S3

    if (tid < 32){
      *(f32x4*)(out + ((size_t)tid * TT + to) * 1024 + dir * 512 + hidx0)
          = *(f32x4*)&outst[tid][0];
      __bf16* hw = hglob + (size_t)(dir * 2 + ((t + 1) & 1)) * 32 * 512;
      *(bf16x4*)(hw + (size_t)tid * 512 + hidx0) = *(bf16x4*)&hbst[tid][0];
    }
    if (tid == 0)
      __hip_atomic_fetch_add(mycnt, 1u, __ATOMIC_RELEASE, __HIP_MEMORY_SCOPE_AGENT);
  }
}

// ---------------------------------------------------------------------------
extern "C" void kernel_launch(void* const* d_in, const int* in_sizes, int n_in,
                              void* d_out, int out_size, void* d_ws, size_t ws_size,
                              hipStream_t stream)
{
  const float* x      = (const float*)d_in[0];
  const void*  mask   = d_in[1];
  const int*   meta_a = (const int*)d_in[2];
  const int*   meta_c = (const int*)d_in[3];
  const float* emb_a  = (const float*)d_in[4];
  const float* emb_c  = (const float*)d_in[5];
  const float* P_W1   = (const float*)d_in[6];
  const float* P_b1   = (const float*)d_in[7];
  const float* P_W2   = (const float*)d_in[8];
  const float* W_ih   = (const float*)d_in[9];
  const float* W_hh   = (const float*)d_in[10];
  const float* bias_f = (const float*)d_in[11];
  const float* W_ih_r = (const float*)d_in[12];
  const float* W_hh_r = (const float*)d_in[13];
  const float* bias_r = (const float*)d_in[14];
  float* out = (float*)d_out;
  char* ws = (char*)d_ws;

  constexpr size_t OFF_C     = 0;           //   1 KB  c_batch
  constexpr size_t OFF_LEN   = 1024;        //  128 B  lengths
  constexpr size_t OFF_CNT   = 2048;        //  256 B  barrier counters
  constexpr size_t OFF_BIAS  = 4096;        //  512 KB mixed biases
  constexpr size_t OFF_H     = 528384;      //  128 KB h double buffers
  constexpr size_t OFF_WHHP  = 659456;      // 33.5 MB basis Whh fragments
  constexpr size_t OFF_XBF   = 34213888;    //  8.4 MB x bf16
  constexpr size_t OFF_WIHM  = 42602496;    //   67 MB mixed Wih (per-dir reuse)
  constexpr size_t OFF_XPROJ = 109711360;   //  134 MB xproj f32 (both dirs)
  constexpr size_t WS_NEED   = 243929088;
  if (ws_size < WS_NEED) return;            // insufficient scratch: bail

  float*        c_b   = (float*)(ws + OFF_C);
  int*          lens  = (int*)(ws + OFF_LEN);
  unsigned int* cntp  = (unsigned int*)(ws + OFF_CNT);
  float*        biasm = (float*)(ws + OFF_BIAS);
  __bf16*       hg    = (__bf16*)(ws + OFF_H);
  __bf16*       whhp  = (__bf16*)(ws + OFF_WHHP);
  __bf16*       xbf   = (__bf16*)(ws + OFF_XBF);
  __bf16*       wihm  = (__bf16*)(ws + OFF_WIHM);
  float*        xproj = (float*)(ws + OFF_XPROJ);

  (void)hipMemsetAsync(cntp, 0, 256, stream);
  k_meta<<<1, 256, 0, stream>>>(mask, meta_a, meta_c, emb_a, emb_c,
                                P_W1, P_b1, P_W2, c_b, lens);
  k_xbf<<<2048, 256, 0, stream>>>(x, xbf);
  k_whhp<<<8192, 256, 0, stream>>>(W_hh, W_hh_r, whhp);
  k_bias<<<512, 256, 0, stream>>>(bias_f, bias_r, c_b, biasm);
  for (int dir = 0; dir < 2; ++dir){
    k_mixwih<<<512, 256, 0, stream>>>(dir ? W_ih_r : W_ih, c_b, wihm);
    k_gemm<<<1024, 256, 0, stream>>>(xbf, wihm,
                                     xproj + (size_t)dir * 32 * TT * 2048);
  }
  k_recur<<<256, 256, 0, stream>>>(whhp, xproj, biasm, c_b, lens, hg, cntp, out);
}

// Round 3
// 2177.546 us; speedup vs baseline: 2.5254x; 2.5254x over previous
//
#include <hip/hip_runtime.h>
#include <hip/hip_bf16.h>
#include <stdint.h>

// ---------------------------------------------------------------------------
// BasisCustBiLSTM: per-sample basis-mixed BiLSTM.
//   k_meta / k_xbf / k_whhp / k_bias / k_mixwih / k_gemm : prep (unchanged)
//   k_recur  : persistent 256-block recurrence. R3: all cross-block h/flag
//              traffic via explicit inline-asm global ops with sc0+sc1
//              (bypass L1+L2 -> MALL coherence point), volatile+memory-clobber
//              ordered, with a VGPR-tying s_waitcnt so consumers can't be
//              scheduled before data arrives. R2's relaxed-atomic version
//              raced stochastically (stale h when a block actually waited).
// ---------------------------------------------------------------------------

typedef __attribute__((ext_vector_type(8))) __bf16 bf16x8;
typedef __attribute__((ext_vector_type(4))) __bf16 bf16x4;
typedef __attribute__((ext_vector_type(4))) float  f32x4;
typedef __attribute__((ext_vector_type(4))) unsigned u32x4;

#define TT 256
#define BBATCH 32

__device__ __forceinline__ __bf16 f2bf(float f){
  unsigned u = __builtin_bit_cast(unsigned, f);
  unsigned short r = (unsigned short)((u + 0x7fffu + ((u >> 16) & 1u)) >> 16);
  return __builtin_bit_cast(__bf16, r);
}
__device__ __forceinline__ float sigm(float x){
  x = fminf(fmaxf(x, -30.f), 30.f);
  return 1.f / (1.f + __expf(-x));
}
__device__ __forceinline__ float tanh_(float x){
  x = fminf(fmaxf(x, -15.f), 15.f);
  float e = __expf(2.f * x);
  return (e - 1.f) / (e + 1.f);
}

// --- coherent (MALL-level) access helpers: sc0 sc1 = bypass L1+L2 ----------
__device__ __forceinline__ u32x4 ld_b128_coh(const void* p){
  u32x4 v;
  asm volatile("global_load_dwordx4 %0, %1, off sc0 sc1"
               : "=v"(v) : "v"(p) : "memory");
  return v;
}
__device__ __forceinline__ unsigned ld_b32_coh_wait(const void* p){
  unsigned v;
  asm volatile("global_load_dword %0, %1, off sc0 sc1\n\ts_waitcnt vmcnt(0)"
               : "=v"(v) : "v"(p) : "memory");
  return v;
}
__device__ __forceinline__ void st_b64_coh(void* p, unsigned long long v){
  asm volatile("global_store_dwordx2 %0, %1, off sc0 sc1"
               :: "v"(p), "v"(v) : "memory");
}
__device__ __forceinline__ void st_b16_coh(void* p, unsigned v){
  asm volatile("global_store_short %0, %1, off sc0 sc1"
               :: "v"(p), "v"(v) : "memory");
}
__device__ __forceinline__ void wait_vm0(){
  asm volatile("s_waitcnt vmcnt(0)" ::: "memory");
}

// ---------------------------------------------------------------------------
__global__ void k_meta(const void* __restrict__ mask,
                       const int* __restrict__ meta_a, const int* __restrict__ meta_c,
                       const float* __restrict__ emb_a, const float* __restrict__ emb_c,
                       const float* __restrict__ W1, const float* __restrict__ b1,
                       const float* __restrict__ W2,
                       float* __restrict__ c_out, int* __restrict__ len_out)
{
  __shared__ int s_bad;
  __shared__ float q_sh[32][128];
  __shared__ float hid[32][64];
  const int tid = threadIdx.x;
  if (tid == 0) s_bad = 0;
  __syncthreads();

  if (tid < 32){
    const unsigned char* m8 = (const unsigned char*)mask;
    int cnt = 0, seen0 = 0, bad = 0;
    for (int t = 0; t < TT; ++t){
      unsigned char v = m8[tid * TT + t];
      if (v > 1) bad = 1;
      if (v){ if (seen0) bad = 1; cnt++; } else seen0 = 1;
    }
    if (tid == 0 && cnt != TT) bad = 1;
    if (bad) atomicAdd(&s_bad, 1);
    len_out[tid] = cnt;
  }
  {
    int b = tid >> 3, p = tid & 7;
    int a = meta_a[b], c = meta_c[b];
    for (int i = 0; i < 16; ++i){
      int qi = p * 16 + i;
      q_sh[b][qi] = (qi < 64) ? emb_a[a * 64 + qi] : emb_c[c * 64 + (qi - 64)];
    }
  }
  __syncthreads();
  if (s_bad){
    if (tid < 32){
      const int* m32 = (const int*)mask;
      int cnt = 0;
      for (int t = 0; t < TT; ++t) if (m32[tid * TT + t]) cnt++;
      len_out[tid] = cnt;
    }
  }
  {
    int b = tid >> 3, kg = tid & 7;
    for (int k8 = 0; k8 < 8; ++k8){
      int k = kg * 8 + k8;
      float s = b1[k];
      for (int i = 0; i < 128; ++i) s += q_sh[b][i] * W1[i * 64 + k];
      hid[b][k] = tanhf(s);
    }
  }
  __syncthreads();
  if (tid < 32){
    float lg[8]; float mx = -1e30f;
    for (int n = 0; n < 8; ++n){
      float s = 0.f;
      for (int k = 0; k < 64; ++k) s += hid[tid][k] * W2[k * 8 + n];
      lg[n] = s; mx = fmaxf(mx, s);
    }
    float den = 0.f;
    for (int n = 0; n < 8; ++n){ lg[n] = expf(lg[n] - mx); den += lg[n]; }
    for (int n = 0; n < 8; ++n) c_out[tid * 8 + n] = lg[n] / den;
  }
}

// ---------------------------------------------------------------------------
__global__ void k_xbf(const float* __restrict__ x, __bf16* __restrict__ xb)
{
  int i = blockIdx.x * 256 + threadIdx.x;
  if (i >= 524288) return;
  f32x4 a = *(const f32x4*)(x + (size_t)i * 8);
  f32x4 b = *(const f32x4*)(x + (size_t)i * 8 + 4);
  bf16x8 o;
  #pragma unroll
  for (int j = 0; j < 4; ++j){ o[j] = f2bf(a[j]); o[4 + j] = f2bf(b[j]); }
  *(bf16x8*)(xb + (size_t)i * 8) = o;
}

// ---------------------------------------------------------------------------
__global__ void k_whhp(const float* __restrict__ whh_f, const float* __restrict__ whh_r,
                       __bf16* __restrict__ outp)
{
  int idx = blockIdx.x * 256 + threadIdx.x;
  int lane = idx & 63; int grp = idx >> 6;
  int n  = grp & 7;  grp >>= 3;
  int kt = grp & 3;  grp >>= 2;
  int wv = grp & 3;  grp >>= 2;
  int wg = grp & 127; int dir = (grp >> 7) & 1;
  int col = lane & 15, quad = lane >> 4;
  int gate = col >> 2, jj = col & 3;
  int g = gate * 512 + wg * 4 + jj;
  int k = (wv * 4 + kt) * 32 + quad * 8;
  const float* Wb = dir ? whh_r : whh_f;
  const float* s = Wb + ((size_t)n * 2048 + g) * 512 + k;
  f32x4 a = *(const f32x4*)s, b = *(const f32x4*)(s + 4);
  bf16x8 o;
  #pragma unroll
  for (int j = 0; j < 4; ++j){ o[j] = f2bf(a[j]); o[4 + j] = f2bf(b[j]); }
  *(bf16x8*)(outp + (size_t)idx * 8) = o;
}

// ---------------------------------------------------------------------------
__global__ void k_bias(const float* __restrict__ b_f, const float* __restrict__ b_r,
                       const float* __restrict__ cb, float* __restrict__ bm)
{
  int idx = blockIdx.x * 256 + threadIdx.x;
  int dir = idx >> 16; int b = (idx >> 11) & 31; int g = idx & 2047;
  const float* bb = dir ? b_r : b_f;
  float s = 0.f;
  #pragma unroll
  for (int n = 0; n < 8; ++n) s += cb[b * 8 + n] * bb[n * 2048 + g];
  bm[idx] = s;
}

// ---------------------------------------------------------------------------
__global__ void k_mixwih(const float* __restrict__ Wb, const float* __restrict__ cb,
                         __bf16* __restrict__ wmix)
{
  __shared__ float cs[256];
  int tid = threadIdx.x;
  cs[tid] = cb[tid];
  __syncthreads();
  int idx = blockIdx.x * 256 + tid;
  int g = idx >> 6, k8 = idx & 63;
  float src[8][8];
  #pragma unroll
  for (int n = 0; n < 8; ++n){
    const float* p = Wb + ((size_t)n * 2048 + g) * 512 + k8 * 8;
    f32x4 lo = *(const f32x4*)p, hi = *(const f32x4*)(p + 4);
    #pragma unroll
    for (int j = 0; j < 4; ++j){ src[n][j] = lo[j]; src[n][4 + j] = hi[j]; }
  }
  for (int b = 0; b < 32; ++b){
    float acc[8] = {0,0,0,0,0,0,0,0};
    #pragma unroll
    for (int n = 0; n < 8; ++n){
      float cn = cs[b * 8 + n];
      #pragma unroll
      for (int j = 0; j < 8; ++j) acc[j] += cn * src[n][j];
    }
    bf16x8 o;
    #pragma unroll
    for (int j = 0; j < 8; ++j) o[j] = f2bf(acc[j]);
    *(bf16x8*)(wmix + ((size_t)b * 2048 + g) * 512 + k8 * 8) = o;
  }
}

// ---------------------------------------------------------------------------
__global__ __launch_bounds__(256) void k_gemm(const __bf16* __restrict__ xb,
                                              const __bf16* __restrict__ wmix,
                                              float* __restrict__ xp)
{
  __shared__ __bf16 As[128][72];
  __shared__ __bf16 Bs[128][72];
  const int tid = threadIdx.x, lane = tid & 63, wv = tid >> 6;
  const int quad = lane >> 4, c16 = lane & 15;
  const int wm_ = wv >> 1, wn_ = wv & 1;
  const int b = blockIdx.x >> 5, tile = blockIdx.x & 31;
  const int m0 = (tile >> 4) * 128, n0 = (tile & 15) * 128;
  const __bf16* Ap = xb + (size_t)b * TT * 512;
  const __bf16* Bp = wmix + (size_t)b * 2048 * 512;
  float* Cp = xp + (size_t)b * TT * 2048;

  f32x4 acc[4][4];
  #pragma unroll
  for (int i = 0; i < 4; ++i)
    #pragma unroll
    for (int j = 0; j < 4; ++j) acc[i][j] = (f32x4){0,0,0,0};

  for (int k0 = 0; k0 < 512; k0 += 64){
    __syncthreads();
    #pragma unroll
    for (int it = 0; it < 4; ++it){
      int r = it * 32 + (tid >> 3), c = (tid & 7) * 8;
      *(bf16x8*)&As[r][c] = *(const bf16x8*)(Ap + (size_t)(m0 + r) * 512 + k0 + c);
      *(bf16x8*)&Bs[r][c] = *(const bf16x8*)(Bp + (size_t)(n0 + r) * 512 + k0 + c);
    }
    __syncthreads();
    #pragma unroll
    for (int kt = 0; kt < 2; ++kt){
      bf16x8 af[4], bfr[4];
      #pragma unroll
      for (int i = 0; i < 4; ++i){
        af[i]  = *(const bf16x8*)&As[wm_ * 64 + i * 16 + c16][kt * 32 + quad * 8];
        bfr[i] = *(const bf16x8*)&Bs[wn_ * 64 + i * 16 + c16][kt * 32 + quad * 8];
      }
      #pragma unroll
      for (int i = 0; i < 4; ++i)
        #pragma unroll
        for (int j = 0; j < 4; ++j)
          acc[i][j] = __builtin_amdgcn_mfma_f32_16x16x32_bf16(af[i], bfr[j], acc[i][j], 0, 0, 0);
    }
  }
  #pragma unroll
  for (int i = 0; i < 4; ++i)
    #pragma unroll
    for (int j = 0; j < 4; ++j){
      int colg = n0 + wn_ * 64 + j * 16 + c16;
      #pragma unroll
      for (int r = 0; r < 4; ++r){
        int row = m0 + wm_ * 64 + i * 16 + quad * 4 + r;
        Cp[(size_t)row * 2048 + colg] = acc[i][j][r];
      }
    }
}

// ---------------------------------------------------------------------------
// k_recur R3: flags = ushort[2][128]. Block wg publishes monotone count:
//   1      after zeroing its slice of h buffer 0
//   t + 2  after writing step-t h into buffer (t+1)&1
// Step-t precondition: all 128 flags >= t+1. Wave 0 polls (1 dword/lane
// covers 2 flags), other waves wait at S0. All h/flag ops are sc0+sc1
// inline asm (MALL-coherent, no L1/L2 staleness, compiler-order-rigid).
// ---------------------------------------------------------------------------
__global__ __launch_bounds__(256, 1) void k_recur(
    const __bf16* __restrict__ whhp,
    const float*  __restrict__ xproj,   // [2][32][256][2048]
    const float*  __restrict__ biasm,   // [2][32][2048]
    const float*  __restrict__ cb,      // [32][8]
    const int*    __restrict__ lens,    // [32]
    __bf16* hglob,                      // [2 dir][2 buf][32][512]
    unsigned short* seq,                // [2][128]
    float* __restrict__ out)            // [32][256][1024]
{
  const int tid = threadIdx.x, lane = tid & 63, wv = tid >> 6;
  const int quad = lane >> 4, c16 = lane & 15;
  const int bid = blockIdx.x, dir = bid >> 7, wg = bid & 127;
  const int hidx0 = wg * 4;

  // basis-weight B fragments -> registers
  bf16x8 bfrag[4][8];
  {
    const __bf16* base = whhp + (size_t)(bid * 4 + wv) * 4 * (8 * 512);
    #pragma unroll
    for (int kt = 0; kt < 4; ++kt)
      #pragma unroll
      for (int n = 0; n < 8; ++n)
        bfrag[kt][n] = *(const bf16x8*)(base + (size_t)(kt * 8 + n) * 512 + lane * 8);
  }
  f32x4 ccv[2][8];
  #pragma unroll
  for (int mt = 0; mt < 2; ++mt)
    #pragma unroll
    for (int n = 0; n < 8; ++n){
      f32x4 v;
      #pragma unroll
      for (int r = 0; r < 4; ++r) v[r] = cb[(mt * 16 + quad * 4 + r) * 8 + n];
      ccv[mt][n] = v;
    }

  const int bb_ = tid >> 2, jj_ = tid & 3;
  float bias_g[4] = {0, 0, 0, 0};
  int mylen = 0;
  float cstate = 0.f;
  if (tid < 128){
    #pragma unroll
    for (int g = 0; g < 4; ++g)
      bias_g[g] = biasm[(size_t)(dir * 32 + bb_) * 2048 + g * 512 + hidx0 + jj_];
    mylen = lens[bb_];
  }

  __shared__ float red[4][2][64][4];
  __shared__ float xg[32][4][4];
  __shared__ float outst[32][4];
  __shared__ __bf16 hbst[32][4];

  unsigned short* sq = seq + dir * 128;

  // publish #1: zero own slice of h buffer 0 (coherent store -> MALL)
  if (tid < 32){
    void* hz = hglob + (size_t)(dir * 2 + 0) * 32 * 512 + (size_t)tid * 512 + hidx0;
    st_b64_coh(hz, 0ull);
  }
  wait_vm0();
  if (tid == 0) st_b16_coh(sq + wg, 1u);

  // prefetch xproj for step 0 (normal cached load)
  f32x4 pf = {0, 0, 0, 0};
  const int b_pf = tid >> 2, g_pf = tid & 3;
  if (tid < 128){
    int to0 = dir ? (TT - 1) : 0;
    pf = *(const f32x4*)(xproj + ((size_t)(dir * 32 + b_pf) * TT + to0) * 2048
                         + g_pf * 512 + hidx0);
  }

  for (int t = 0; t < TT; ++t){
    const int to = dir ? (TT - 1 - t) : t;

    // ---- S0 barrier: wave 0 polls all 128 flags (2 per lane, one dword) ----
    if (wv == 0){
      const void* sp = (const unsigned*)(const void*)sq + lane;
      const unsigned tgt = (unsigned)(t + 1);
      while (true){
        unsigned v = ld_b32_coh_wait(sp);
        if (__all((int)(((v & 0xffffu) >= tgt) & ((v >> 16) >= tgt)))) break;
      }
    }
    __syncthreads();     // S0

    // ---- h fragments: coherent 16B loads, then tying waitcnt ----
    const __bf16* hr = hglob + (size_t)(dir * 2 + (t & 1)) * 32 * 512;
    u32x4 hv[8];
    #pragma unroll
    for (int mt = 0; mt < 2; ++mt)
      #pragma unroll
      for (int kt = 0; kt < 4; ++kt)
        hv[mt * 4 + kt] = ld_b128_coh(hr + (size_t)(mt * 16 + c16) * 512
                                      + (wv * 4 + kt) * 32 + quad * 8);
    asm volatile("s_waitcnt vmcnt(0)"
                 : "+v"(hv[0]), "+v"(hv[1]), "+v"(hv[2]), "+v"(hv[3]),
                   "+v"(hv[4]), "+v"(hv[5]), "+v"(hv[6]), "+v"(hv[7])
                 :: "memory");
    bf16x8 af[2][4];
    #pragma unroll
    for (int mt = 0; mt < 2; ++mt)
      #pragma unroll
      for (int kt = 0; kt < 4; ++kt)
        af[mt][kt] = __builtin_bit_cast(bf16x8, hv[mt * 4 + kt]);

    f32x4 acc[8][2];
    #pragma unroll
    for (int n = 0; n < 8; ++n){ acc[n][0] = (f32x4){0,0,0,0}; acc[n][1] = (f32x4){0,0,0,0}; }
    #pragma unroll
    for (int kt = 0; kt < 4; ++kt)
      #pragma unroll
      for (int n = 0; n < 8; ++n){
        acc[n][0] = __builtin_amdgcn_mfma_f32_16x16x32_bf16(af[0][kt], bfrag[kt][n], acc[n][0], 0, 0, 0);
        acc[n][1] = __builtin_amdgcn_mfma_f32_16x16x32_bf16(af[1][kt], bfrag[kt][n], acc[n][1], 0, 0, 0);
      }
    f32x4 mix0 = {0,0,0,0}, mix1 = {0,0,0,0};
    #pragma unroll
    for (int n = 0; n < 8; ++n){
      mix0 += ccv[0][n] * acc[n][0];
      mix1 += ccv[1][n] * acc[n][1];
    }
    *(f32x4*)&red[wv][0][lane][0] = mix0;
    *(f32x4*)&red[wv][1][lane][0] = mix1;
    if (tid < 128)
      *(f32x4*)&xg[b_pf][g_pf][0] = pf;
    if (t < TT - 1 && tid < 128){
      int ton = dir ? (TT - 2 - t) : (t + 1);
      pf = *(const f32x4*)(xproj + ((size_t)(dir * 32 + b_pf) * TT + ton) * 2048
                           + g_pf * 512 + hidx0);
    }
    __syncthreads();     // S2

    if (tid < 128){
      const int r = bb_ & 15, mt = bb_ >> 4, rg = r & 3, qp = r >> 2;
      float gv[4];
      #pragma unroll
      for (int g = 0; g < 4; ++g){
        int li = qp * 16 + g * 4 + jj_;
        float s = red[0][mt][li][rg] + red[1][mt][li][rg]
                + red[2][mt][li][rg] + red[3][mt][li][rg];
        gv[g] = s + xg[bb_][g][jj_] + bias_g[g];
      }
      float i_ = sigm(gv[0]);
      float f_ = sigm(gv[1]);
      float g_ = tanh_(gv[2]);
      float o_ = sigm(gv[3]);
      bool valid = (to < mylen);
      float cy = valid ? (f_ * cstate + i_ * g_) : 0.f;
      float hy = valid ? (o_ * tanh_(cy)) : 0.f;
      cstate = cy;
      outst[bb_][jj_] = hy;
      hbst[bb_][jj_] = f2bf(hy);
    }
    __syncthreads();     // S3

    // writer chain (wave 0): h store -> drain -> publish; out store after.
    if (tid < 32){
      __bf16* hw = hglob + (size_t)(dir * 2 + ((t + 1) & 1)) * 32 * 512;
      unsigned long long hvv =
          __builtin_bit_cast(unsigned long long, *(bf16x4*)&hbst[tid][0]);
      st_b64_coh(hw + (size_t)tid * 512 + hidx0, hvv);
    }
    wait_vm0();
    if (tid == 0) st_b16_coh(sq + wg, (unsigned)(t + 2));
    if (tid < 32){
      *(f32x4*)(out + ((size_t)tid * TT + to) * 1024 + dir * 512 + hidx0)
          = *(f32x4*)&outst[tid][0];
    }
  }
}

// ---------------------------------------------------------------------------
extern "C" void kernel_launch(void* const* d_in, const int* in_sizes, int n_in,
                              void* d_out, int out_size, void* d_ws, size_t ws_size,
                              hipStream_t stream)
{
  const float* x      = (const float*)d_in[0];
  const void*  mask   = d_in[1];
  const int*   meta_a = (const int*)d_in[2];
  const int*   meta_c = (const int*)d_in[3];
  const float* emb_a  = (const float*)d_in[4];
  const float* emb_c  = (const float*)d_in[5];
  const float* P_W1   = (const float*)d_in[6];
  const float* P_b1   = (const float*)d_in[7];
  const float* P_W2   = (const float*)d_in[8];
  const float* W_ih   = (const float*)d_in[9];
  const float* W_hh   = (const float*)d_in[10];
  const float* bias_f = (const float*)d_in[11];
  const float* W_ih_r = (const float*)d_in[12];
  const float* W_hh_r = (const float*)d_in[13];
  const float* bias_r = (const float*)d_in[14];
  float* out = (float*)d_out;
  char* ws = (char*)d_ws;

  constexpr size_t OFF_C     = 0;           //   1 KB  c_batch
  constexpr size_t OFF_LEN   = 1024;        //  128 B  lengths
  constexpr size_t OFF_SEQ   = 2048;        //  512 B  seq flags [2][128] u16
  constexpr size_t OFF_BIAS  = 4096;        //  512 KB mixed biases
  constexpr size_t OFF_H     = 528384;      //  128 KB h double buffers
  constexpr size_t OFF_WHHP  = 659456;      // 33.5 MB basis Whh fragments
  constexpr size_t OFF_XBF   = 34213888;    //  8.4 MB x bf16
  constexpr size_t OFF_WIHM  = 42602496;    //   67 MB mixed Wih (per-dir reuse)
  constexpr size_t OFF_XPROJ = 109711360;   //  134 MB xproj f32 (both dirs)
  constexpr size_t WS_NEED   = 243929088;
  if (ws_size < WS_NEED) return;

  float*          c_b   = (float*)(ws + OFF_C);
  int*            lens  = (int*)(ws + OFF_LEN);
  unsigned short* seqp  = (unsigned short*)(ws + OFF_SEQ);
  float*          biasm = (float*)(ws + OFF_BIAS);
  __bf16*         hg    = (__bf16*)(ws + OFF_H);
  __bf16*         whhp  = (__bf16*)(ws + OFF_WHHP);
  __bf16*         xbf   = (__bf16*)(ws + OFF_XBF);
  __bf16*         wihm  = (__bf16*)(ws + OFF_WIHM);
  float*          xproj = (float*)(ws + OFF_XPROJ);

  (void)hipMemsetAsync(seqp, 0, 512, stream);
  k_meta<<<1, 256, 0, stream>>>(mask, meta_a, meta_c, emb_a, emb_c,
                                P_W1, P_b1, P_W2, c_b, lens);
  k_xbf<<<2048, 256, 0, stream>>>(x, xbf);
  k_whhp<<<8192, 256, 0, stream>>>(W_hh, W_hh_r, whhp);
  k_bias<<<512, 256, 0, stream>>>(bias_f, bias_r, c_b, biasm);
  for (int dir = 0; dir < 2; ++dir){
    k_mixwih<<<512, 256, 0, stream>>>(dir ? W_ih_r : W_ih, c_b, wihm);
    k_gemm<<<1024, 256, 0, stream>>>(xbf, wihm,
                                     xproj + (size_t)dir * 32 * TT * 2048);
  }
  k_recur<<<256, 256, 0, stream>>>(whhp, xproj, biasm, c_b, lens, hg, seqp, out);
}

// Round 4
// 1931.109 us; speedup vs baseline: 2.8476x; 1.1276x over previous
//
#include <hip/hip_runtime.h>
#include <hip/hip_bf16.h>
#include <stdint.h>

// ---------------------------------------------------------------------------
// BasisCustBiLSTM: per-sample basis-mixed BiLSTM.
//   k_meta / k_xbf / k_whhp / k_bias / k_mixwih / k_gemm : prep (unchanged)
//   k_recur R4:
//     - xproj prefetch + out store moved AFTER flag publish (R3 serialized an
//       HBM-latency prefetch into the writer drain each step)
//     - XCD-aware wg swizzle: blocks sharing a 64B xproj/out line sit on one
//       XCD -> line fetched once (R3: 4x cross-XCD amplification, 611 MB)
//     - byte flags (2 lines) polled by every wave with coalesced dword loads;
//       no S0 barrier. Wrap-safe: flag spread <= 1 step.
// ---------------------------------------------------------------------------

typedef __attribute__((ext_vector_type(8))) __bf16 bf16x8;
typedef __attribute__((ext_vector_type(4))) __bf16 bf16x4;
typedef __attribute__((ext_vector_type(4))) float  f32x4;
typedef __attribute__((ext_vector_type(4))) unsigned u32x4;

#define TT 256
#define BBATCH 32

__device__ __forceinline__ __bf16 f2bf(float f){
  unsigned u = __builtin_bit_cast(unsigned, f);
  unsigned short r = (unsigned short)((u + 0x7fffu + ((u >> 16) & 1u)) >> 16);
  return __builtin_bit_cast(__bf16, r);
}
__device__ __forceinline__ float sigm(float x){
  x = fminf(fmaxf(x, -30.f), 30.f);
  return 1.f / (1.f + __expf(-x));
}
__device__ __forceinline__ float tanh_(float x){
  x = fminf(fmaxf(x, -15.f), 15.f);
  float e = __expf(2.f * x);
  return (e - 1.f) / (e + 1.f);
}

// --- coherent (MALL-level) access helpers: sc0 sc1 = bypass L1+L2 ----------
__device__ __forceinline__ u32x4 ld_b128_coh(const void* p){
  u32x4 v;
  asm volatile("global_load_dwordx4 %0, %1, off sc0 sc1"
               : "=v"(v) : "v"(p) : "memory");
  return v;
}
__device__ __forceinline__ unsigned ld_b32_coh_wait(const void* p){
  unsigned v;
  asm volatile("global_load_dword %0, %1, off sc0 sc1\n\ts_waitcnt vmcnt(0)"
               : "=v"(v) : "v"(p) : "memory");
  return v;
}
__device__ __forceinline__ void st_b64_coh(void* p, unsigned long long v){
  asm volatile("global_store_dwordx2 %0, %1, off sc0 sc1"
               :: "v"(p), "v"(v) : "memory");
}
__device__ __forceinline__ void st_b8_coh(void* p, unsigned v){
  asm volatile("global_store_byte %0, %1, off sc0 sc1"
               :: "v"(p), "v"(v) : "memory");
}
__device__ __forceinline__ void wait_vm0(){
  asm volatile("s_waitcnt vmcnt(0)" ::: "memory");
}

// ---------------------------------------------------------------------------
__global__ void k_meta(const void* __restrict__ mask,
                       const int* __restrict__ meta_a, const int* __restrict__ meta_c,
                       const float* __restrict__ emb_a, const float* __restrict__ emb_c,
                       const float* __restrict__ W1, const float* __restrict__ b1,
                       const float* __restrict__ W2,
                       float* __restrict__ c_out, int* __restrict__ len_out)
{
  __shared__ int s_bad;
  __shared__ float q_sh[32][128];
  __shared__ float hid[32][64];
  const int tid = threadIdx.x;
  if (tid == 0) s_bad = 0;
  __syncthreads();

  if (tid < 32){
    const unsigned char* m8 = (const unsigned char*)mask;
    int cnt = 0, seen0 = 0, bad = 0;
    for (int t = 0; t < TT; ++t){
      unsigned char v = m8[tid * TT + t];
      if (v > 1) bad = 1;
      if (v){ if (seen0) bad = 1; cnt++; } else seen0 = 1;
    }
    if (tid == 0 && cnt != TT) bad = 1;
    if (bad) atomicAdd(&s_bad, 1);
    len_out[tid] = cnt;
  }
  {
    int b = tid >> 3, p = tid & 7;
    int a = meta_a[b], c = meta_c[b];
    for (int i = 0; i < 16; ++i){
      int qi = p * 16 + i;
      q_sh[b][qi] = (qi < 64) ? emb_a[a * 64 + qi] : emb_c[c * 64 + (qi - 64)];
    }
  }
  __syncthreads();
  if (s_bad){
    if (tid < 32){
      const int* m32 = (const int*)mask;
      int cnt = 0;
      for (int t = 0; t < TT; ++t) if (m32[tid * TT + t]) cnt++;
      len_out[tid] = cnt;
    }
  }
  {
    int b = tid >> 3, kg = tid & 7;
    for (int k8 = 0; k8 < 8; ++k8){
      int k = kg * 8 + k8;
      float s = b1[k];
      for (int i = 0; i < 128; ++i) s += q_sh[b][i] * W1[i * 64 + k];
      hid[b][k] = tanhf(s);
    }
  }
  __syncthreads();
  if (tid < 32){
    float lg[8]; float mx = -1e30f;
    for (int n = 0; n < 8; ++n){
      float s = 0.f;
      for (int k = 0; k < 64; ++k) s += hid[tid][k] * W2[k * 8 + n];
      lg[n] = s; mx = fmaxf(mx, s);
    }
    float den = 0.f;
    for (int n = 0; n < 8; ++n){ lg[n] = expf(lg[n] - mx); den += lg[n]; }
    for (int n = 0; n < 8; ++n) c_out[tid * 8 + n] = lg[n] / den;
  }
}

// ---------------------------------------------------------------------------
__global__ void k_xbf(const float* __restrict__ x, __bf16* __restrict__ xb)
{
  int i = blockIdx.x * 256 + threadIdx.x;
  if (i >= 524288) return;
  f32x4 a = *(const f32x4*)(x + (size_t)i * 8);
  f32x4 b = *(const f32x4*)(x + (size_t)i * 8 + 4);
  bf16x8 o;
  #pragma unroll
  for (int j = 0; j < 4; ++j){ o[j] = f2bf(a[j]); o[4 + j] = f2bf(b[j]); }
  *(bf16x8*)(xb + (size_t)i * 8) = o;
}

// ---------------------------------------------------------------------------
__global__ void k_whhp(const float* __restrict__ whh_f, const float* __restrict__ whh_r,
                       __bf16* __restrict__ outp)
{
  int idx = blockIdx.x * 256 + threadIdx.x;
  int lane = idx & 63; int grp = idx >> 6;
  int n  = grp & 7;  grp >>= 3;
  int kt = grp & 3;  grp >>= 2;
  int wv = grp & 3;  grp >>= 2;
  int wg = grp & 127; int dir = (grp >> 7) & 1;
  int col = lane & 15, quad = lane >> 4;
  int gate = col >> 2, jj = col & 3;
  int g = gate * 512 + wg * 4 + jj;
  int k = (wv * 4 + kt) * 32 + quad * 8;
  const float* Wb = dir ? whh_r : whh_f;
  const float* s = Wb + ((size_t)n * 2048 + g) * 512 + k;
  f32x4 a = *(const f32x4*)s, b = *(const f32x4*)(s + 4);
  bf16x8 o;
  #pragma unroll
  for (int j = 0; j < 4; ++j){ o[j] = f2bf(a[j]); o[4 + j] = f2bf(b[j]); }
  *(bf16x8*)(outp + (size_t)idx * 8) = o;
}

// ---------------------------------------------------------------------------
__global__ void k_bias(const float* __restrict__ b_f, const float* __restrict__ b_r,
                       const float* __restrict__ cb, float* __restrict__ bm)
{
  int idx = blockIdx.x * 256 + threadIdx.x;
  int dir = idx >> 16; int b = (idx >> 11) & 31; int g = idx & 2047;
  const float* bb = dir ? b_r : b_f;
  float s = 0.f;
  #pragma unroll
  for (int n = 0; n < 8; ++n) s += cb[b * 8 + n] * bb[n * 2048 + g];
  bm[idx] = s;
}

// ---------------------------------------------------------------------------
__global__ void k_mixwih(const float* __restrict__ Wb, const float* __restrict__ cb,
                         __bf16* __restrict__ wmix)
{
  __shared__ float cs[256];
  int tid = threadIdx.x;
  cs[tid] = cb[tid];
  __syncthreads();
  int idx = blockIdx.x * 256 + tid;
  int g = idx >> 6, k8 = idx & 63;
  float src[8][8];
  #pragma unroll
  for (int n = 0; n < 8; ++n){
    const float* p = Wb + ((size_t)n * 2048 + g) * 512 + k8 * 8;
    f32x4 lo = *(const f32x4*)p, hi = *(const f32x4*)(p + 4);
    #pragma unroll
    for (int j = 0; j < 4; ++j){ src[n][j] = lo[j]; src[n][4 + j] = hi[j]; }
  }
  for (int b = 0; b < 32; ++b){
    float acc[8] = {0,0,0,0,0,0,0,0};
    #pragma unroll
    for (int n = 0; n < 8; ++n){
      float cn = cs[b * 8 + n];
      #pragma unroll
      for (int j = 0; j < 8; ++j) acc[j] += cn * src[n][j];
    }
    bf16x8 o;
    #pragma unroll
    for (int j = 0; j < 8; ++j) o[j] = f2bf(acc[j]);
    *(bf16x8*)(wmix + ((size_t)b * 2048 + g) * 512 + k8 * 8) = o;
  }
}

// ---------------------------------------------------------------------------
__global__ __launch_bounds__(256) void k_gemm(const __bf16* __restrict__ xb,
                                              const __bf16* __restrict__ wmix,
                                              float* __restrict__ xp)
{
  __shared__ __bf16 As[128][72];
  __shared__ __bf16 Bs[128][72];
  const int tid = threadIdx.x, lane = tid & 63, wv = tid >> 6;
  const int quad = lane >> 4, c16 = lane & 15;
  const int wm_ = wv >> 1, wn_ = wv & 1;
  const int b = blockIdx.x >> 5, tile = blockIdx.x & 31;
  const int m0 = (tile >> 4) * 128, n0 = (tile & 15) * 128;
  const __bf16* Ap = xb + (size_t)b * TT * 512;
  const __bf16* Bp = wmix + (size_t)b * 2048 * 512;
  float* Cp = xp + (size_t)b * TT * 2048;

  f32x4 acc[4][4];
  #pragma unroll
  for (int i = 0; i < 4; ++i)
    #pragma unroll
    for (int j = 0; j < 4; ++j) acc[i][j] = (f32x4){0,0,0,0};

  for (int k0 = 0; k0 < 512; k0 += 64){
    __syncthreads();
    #pragma unroll
    for (int it = 0; it < 4; ++it){
      int r = it * 32 + (tid >> 3), c = (tid & 7) * 8;
      *(bf16x8*)&As[r][c] = *(const bf16x8*)(Ap + (size_t)(m0 + r) * 512 + k0 + c);
      *(bf16x8*)&Bs[r][c] = *(const bf16x8*)(Bp + (size_t)(n0 + r) * 512 + k0 + c);
    }
    __syncthreads();
    #pragma unroll
    for (int kt = 0; kt < 2; ++kt){
      bf16x8 af[4], bfr[4];
      #pragma unroll
      for (int i = 0; i < 4; ++i){
        af[i]  = *(const bf16x8*)&As[wm_ * 64 + i * 16 + c16][kt * 32 + quad * 8];
        bfr[i] = *(const bf16x8*)&Bs[wn_ * 64 + i * 16 + c16][kt * 32 + quad * 8];
      }
      #pragma unroll
      for (int i = 0; i < 4; ++i)
        #pragma unroll
        for (int j = 0; j < 4; ++j)
          acc[i][j] = __builtin_amdgcn_mfma_f32_16x16x32_bf16(af[i], bfr[j], acc[i][j], 0, 0, 0);
    }
  }
  #pragma unroll
  for (int i = 0; i < 4; ++i)
    #pragma unroll
    for (int j = 0; j < 4; ++j){
      int colg = n0 + wn_ * 64 + j * 16 + c16;
      #pragma unroll
      for (int r = 0; r < 4; ++r){
        int row = m0 + wm_ * 64 + i * 16 + quad * 4 + r;
        Cp[(size_t)row * 2048 + colg] = acc[i][j][r];
      }
    }
}

// ---------------------------------------------------------------------------
// k_recur R4. flags = u8[2][128]; block wg publishes (monotone, mod 256):
//   1    after zeroing its slice of h buffer 0
//   t+2  after writing step-t h into buffer (t+1)&1
// Step-t precondition: all 128 flags >= t+1. Spread <= 1 (a block publishes p
// only if slowest >= p-1), so mod-256 check "byte != (t)&0xff" is exact.
// wg is XCD-swizzled: wg = (bid&7)*16 + (bid>>3)&15, so wg,wg+1..+3 (which
// share 64B xproj/out lines) sit on ONE XCD -> lines fetched once.
// ---------------------------------------------------------------------------
__global__ __launch_bounds__(256, 1) void k_recur(
    const __bf16* __restrict__ whhp,
    const float*  __restrict__ xproj,   // [2][32][256][2048]
    const float*  __restrict__ biasm,   // [2][32][2048]
    const float*  __restrict__ cb,      // [32][8]
    const int*    __restrict__ lens,    // [32]
    __bf16* hglob,                      // [2 dir][2 buf][32][512]
    unsigned char* seq,                 // [2][128] byte flags
    float* __restrict__ out)            // [32][256][1024]
{
  const int tid = threadIdx.x, lane = tid & 63, wv = tid >> 6;
  const int quad = lane >> 4, c16 = lane & 15;
  const int bid = blockIdx.x, dir = bid >> 7;
  const int b7 = bid & 127;
  const int wg = ((b7 & 7) << 4) | (b7 >> 3);   // XCD-aware swizzle
  const int hidx0 = wg * 4;

  // basis-weight B fragments -> registers (logical-wg indexed)
  bf16x8 bfrag[4][8];
  {
    const __bf16* base = whhp + (size_t)((dir * 128 + wg) * 4 + wv) * 4 * (8 * 512);
    #pragma unroll
    for (int kt = 0; kt < 4; ++kt)
      #pragma unroll
      for (int n = 0; n < 8; ++n)
        bfrag[kt][n] = *(const bf16x8*)(base + (size_t)(kt * 8 + n) * 512 + lane * 8);
  }
  f32x4 ccv[2][8];
  #pragma unroll
  for (int mt = 0; mt < 2; ++mt)
    #pragma unroll
    for (int n = 0; n < 8; ++n){
      f32x4 v;
      #pragma unroll
      for (int r = 0; r < 4; ++r) v[r] = cb[(mt * 16 + quad * 4 + r) * 8 + n];
      ccv[mt][n] = v;
    }

  const int bb_ = tid >> 2, jj_ = tid & 3;
  float bias_g[4] = {0, 0, 0, 0};
  int mylen = 0;
  float cstate = 0.f;
  if (tid < 128){
    #pragma unroll
    for (int g = 0; g < 4; ++g)
      bias_g[g] = biasm[(size_t)(dir * 32 + bb_) * 2048 + g * 512 + hidx0 + jj_];
    mylen = lens[bb_];
  }

  __shared__ float red[4][2][64][4];
  __shared__ float xg[32][4][4];
  __shared__ float outst[32][4];
  __shared__ __bf16 hbst[32][4];

  unsigned char* sq = seq + dir * 128;

  // publish #1: zero own slice of h buffer 0 (coherent store -> MALL)
  if (tid < 32){
    void* hz = hglob + (size_t)(dir * 2 + 0) * 32 * 512 + (size_t)tid * 512 + hidx0;
    st_b64_coh(hz, 0ull);
  }
  wait_vm0();
  if (tid == 0) st_b8_coh(sq + wg, 1u);

  // prefetch xproj for step 0 (normal cached load)
  f32x4 pf = {0, 0, 0, 0};
  const int b_pf = tid >> 2, g_pf = tid & 3;
  if (tid < 128){
    int to0 = dir ? (TT - 1) : 0;
    pf = *(const f32x4*)(xproj + ((size_t)(dir * 32 + b_pf) * TT + to0) * 2048
                         + g_pf * 512 + hidx0);
  }

  for (int t = 0; t < TT; ++t){
    const int to = dir ? (TT - 1 - t) : t;

    // ---- barrier: every wave polls the 128 byte flags (2 coalesced lines).
    // lag value = t (mod 256); ready iff no byte equals it.
    {
      const unsigned lagpat = 0x01010101u * (unsigned)((unsigned char)t);
      const unsigned* fp = (const unsigned*)(const void*)sq + (lane & 31);
      while (true){
        unsigned v = ld_b32_coh_wait(fp);
        unsigned z = v ^ lagpat;
        unsigned haslag = (z - 0x01010101u) & ~z & 0x80808080u;
        if (__all((int)(haslag == 0u))) break;
      }
    }

    // ---- h fragments: coherent 16B loads, then tying waitcnt ----
    const __bf16* hr = hglob + (size_t)(dir * 2 + (t & 1)) * 32 * 512;
    u32x4 hv[8];
    #pragma unroll
    for (int mt = 0; mt < 2; ++mt)
      #pragma unroll
      for (int kt = 0; kt < 4; ++kt)
        hv[mt * 4 + kt] = ld_b128_coh(hr + (size_t)(mt * 16 + c16) * 512
                                      + (wv * 4 + kt) * 32 + quad * 8);
    asm volatile("s_waitcnt vmcnt(0)"
                 : "+v"(hv[0]), "+v"(hv[1]), "+v"(hv[2]), "+v"(hv[3]),
                   "+v"(hv[4]), "+v"(hv[5]), "+v"(hv[6]), "+v"(hv[7])
                 :: "memory");
    bf16x8 af[2][4];
    #pragma unroll
    for (int mt = 0; mt < 2; ++mt)
      #pragma unroll
      for (int kt = 0; kt < 4; ++kt)
        af[mt][kt] = __builtin_bit_cast(bf16x8, hv[mt * 4 + kt]);

    f32x4 acc[8][2];
    #pragma unroll
    for (int n = 0; n < 8; ++n){ acc[n][0] = (f32x4){0,0,0,0}; acc[n][1] = (f32x4){0,0,0,0}; }
    #pragma unroll
    for (int kt = 0; kt < 4; ++kt)
      #pragma unroll
      for (int n = 0; n < 8; ++n){
        acc[n][0] = __builtin_amdgcn_mfma_f32_16x16x32_bf16(af[0][kt], bfrag[kt][n], acc[n][0], 0, 0, 0);
        acc[n][1] = __builtin_amdgcn_mfma_f32_16x16x32_bf16(af[1][kt], bfrag[kt][n], acc[n][1], 0, 0, 0);
      }
    f32x4 mix0 = {0,0,0,0}, mix1 = {0,0,0,0};
    #pragma unroll
    for (int n = 0; n < 8; ++n){
      mix0 += ccv[0][n] * acc[n][0];
      mix1 += ccv[1][n] * acc[n][1];
    }
    *(f32x4*)&red[wv][0][lane][0] = mix0;
    *(f32x4*)&red[wv][1][lane][0] = mix1;
    if (tid < 128)
      *(f32x4*)&xg[b_pf][g_pf][0] = pf;
    __syncthreads();     // S2

    if (tid < 128){
      const int r = bb_ & 15, mt = bb_ >> 4, rg = r & 3, qp = r >> 2;
      float gv[4];
      #pragma unroll
      for (int g = 0; g < 4; ++g){
        int li = qp * 16 + g * 4 + jj_;
        float s = red[0][mt][li][rg] + red[1][mt][li][rg]
                + red[2][mt][li][rg] + red[3][mt][li][rg];
        gv[g] = s + xg[bb_][g][jj_] + bias_g[g];
      }
      float i_ = sigm(gv[0]);
      float f_ = sigm(gv[1]);
      float g_ = tanh_(gv[2]);
      float o_ = sigm(gv[3]);
      bool valid = (to < mylen);
      float cy = valid ? (f_ * cstate + i_ * g_) : 0.f;
      float hy = valid ? (o_ * tanh_(cy)) : 0.f;
      cstate = cy;
      outst[bb_][jj_] = hy;
      hbst[bb_][jj_] = f2bf(hy);
    }
    __syncthreads();     // S3

    // writer chain: h store -> drain (h stores only; prefetch/out are a full
    // step old by now) -> publish flag. Prefetch + out AFTER the publish.
    if (tid < 32){
      __bf16* hw = hglob + (size_t)(dir * 2 + ((t + 1) & 1)) * 32 * 512;
      unsigned long long hvv =
          __builtin_bit_cast(unsigned long long, *(bf16x4*)&hbst[tid][0]);
      st_b64_coh(hw + (size_t)tid * 512 + hidx0, hvv);
    }
    wait_vm0();
    if (tid == 0) st_b8_coh(sq + wg, (unsigned)((unsigned char)(t + 2)));

    if (t < TT - 1 && tid < 128){
      int ton = dir ? (TT - 2 - t) : (t + 1);
      pf = *(const f32x4*)(xproj + ((size_t)(dir * 32 + b_pf) * TT + ton) * 2048
                           + g_pf * 512 + hidx0);
    }
    if (tid < 32){
      *(f32x4*)(out + ((size_t)tid * TT + to) * 1024 + dir * 512 + hidx0)
          = *(f32x4*)&outst[tid][0];
    }
  }
}

// ---------------------------------------------------------------------------
extern "C" void kernel_launch(void* const* d_in, const int* in_sizes, int n_in,
                              void* d_out, int out_size, void* d_ws, size_t ws_size,
                              hipStream_t stream)
{
  const float* x      = (const float*)d_in[0];
  const void*  mask   = d_in[1];
  const int*   meta_a = (const int*)d_in[2];
  const int*   meta_c = (const int*)d_in[3];
  const float* emb_a  = (const float*)d_in[4];
  const float* emb_c  = (const float*)d_in[5];
  const float* P_W1   = (const float*)d_in[6];
  const float* P_b1   = (const float*)d_in[7];
  const float* P_W2   = (const float*)d_in[8];
  const float* W_ih   = (const float*)d_in[9];
  const float* W_hh   = (const float*)d_in[10];
  const float* bias_f = (const float*)d_in[11];
  const float* W_ih_r = (const float*)d_in[12];
  const float* W_hh_r = (const float*)d_in[13];
  const float* bias_r = (const float*)d_in[14];
  float* out = (float*)d_out;
  char* ws = (char*)d_ws;

  constexpr size_t OFF_C     = 0;           //   1 KB  c_batch
  constexpr size_t OFF_LEN   = 1024;        //  128 B  lengths
  constexpr size_t OFF_SEQ   = 2048;        //  256 B  byte flags [2][128]
  constexpr size_t OFF_BIAS  = 4096;        //  512 KB mixed biases
  constexpr size_t OFF_H     = 528384;      //  128 KB h double buffers
  constexpr size_t OFF_WHHP  = 659456;      // 33.5 MB basis Whh fragments
  constexpr size_t OFF_XBF   = 34213888;    //  8.4 MB x bf16
  constexpr size_t OFF_WIHM  = 42602496;    //   67 MB mixed Wih (per-dir reuse)
  constexpr size_t OFF_XPROJ = 109711360;   //  134 MB xproj f32 (both dirs)
  constexpr size_t WS_NEED   = 243929088;
  if (ws_size < WS_NEED) return;

  float*         c_b   = (float*)(ws + OFF_C);
  int*           lens  = (int*)(ws + OFF_LEN);
  unsigned char* seqp  = (unsigned char*)(ws + OFF_SEQ);
  float*         biasm = (float*)(ws + OFF_BIAS);
  __bf16*        hg    = (__bf16*)(ws + OFF_H);
  __bf16*        whhp  = (__bf16*)(ws + OFF_WHHP);
  __bf16*        xbf   = (__bf16*)(ws + OFF_XBF);
  __bf16*        wihm  = (__bf16*)(ws + OFF_WIHM);
  float*         xproj = (float*)(ws + OFF_XPROJ);

  (void)hipMemsetAsync(seqp, 0, 256, stream);
  k_meta<<<1, 256, 0, stream>>>(mask, meta_a, meta_c, emb_a, emb_c,
                                P_W1, P_b1, P_W2, c_b, lens);
  k_xbf<<<2048, 256, 0, stream>>>(x, xbf);
  k_whhp<<<8192, 256, 0, stream>>>(W_hh, W_hh_r, whhp);
  k_bias<<<512, 256, 0, stream>>>(bias_f, bias_r, c_b, biasm);
  for (int dir = 0; dir < 2; ++dir){
    k_mixwih<<<512, 256, 0, stream>>>(dir ? W_ih_r : W_ih, c_b, wihm);
    k_gemm<<<1024, 256, 0, stream>>>(xbf, wihm,
                                     xproj + (size_t)dir * 32 * TT * 2048);
  }
  k_recur<<<256, 256, 0, stream>>>(whhp, xproj, biasm, c_b, lens, hg, seqp, out);
}

// Round 5
// 1717.610 us; speedup vs baseline: 3.2016x; 1.1243x over previous
//
#include <hip/hip_runtime.h>
#include <hip/hip_bf16.h>
#include <stdint.h>

// ---------------------------------------------------------------------------
// BasisCustBiLSTM: per-sample basis-mixed BiLSTM.
//   k_meta / k_xbf / k_whhp / k_bias / k_mixwih / k_gemm : prep (unchanged)
//   k_recur R5: tag-embedded h records replace flags+ack.
//     record[buf][sample][wg] = {4x bf16 h, u32 tag, pad} (16 B, one dwordx4,
//     atomic visibility). Readers poll their own fragment records until
//     tag == t. No store-drain, no flag array, no separate publish: removes
//     2 of the 3 serialized MALL round-trips per step that R4 measured
//     (6.3 us/step at ~7% MfmaUtil with near-ideal traffic).
//     Wave roles: w0-1 prefetch+cell, w2 out-store, w3 h-record store.
// ---------------------------------------------------------------------------

typedef __attribute__((ext_vector_type(8))) __bf16 bf16x8;
typedef __attribute__((ext_vector_type(4))) __bf16 bf16x4;
typedef __attribute__((ext_vector_type(4))) float  f32x4;
typedef __attribute__((ext_vector_type(4))) unsigned u32x4;

#define TT 256
#define BBATCH 32

__device__ __forceinline__ __bf16 f2bf(float f){
  unsigned u = __builtin_bit_cast(unsigned, f);
  unsigned short r = (unsigned short)((u + 0x7fffu + ((u >> 16) & 1u)) >> 16);
  return __builtin_bit_cast(__bf16, r);
}
__device__ __forceinline__ float sigm(float x){
  x = fminf(fmaxf(x, -30.f), 30.f);
  return 1.f / (1.f + __expf(-x));
}
__device__ __forceinline__ float tanh_(float x){
  x = fminf(fmaxf(x, -15.f), 15.f);
  float e = __expf(2.f * x);
  return (e - 1.f) / (e + 1.f);
}

// --- coherent (MALL-level) access helpers: sc0 sc1 = bypass L1+L2 ----------
__device__ __forceinline__ u32x4 ld_b128_coh(const void* p){
  u32x4 v;
  asm volatile("global_load_dwordx4 %0, %1, off sc0 sc1"
               : "=v"(v) : "v"(p) : "memory");
  return v;
}
__device__ __forceinline__ void st_b128_coh(void* p, u32x4 v){
  asm volatile("global_store_dwordx4 %0, %1, off sc0 sc1"
               :: "v"(p), "v"(v) : "memory");
}

// ---------------------------------------------------------------------------
__global__ void k_meta(const void* __restrict__ mask,
                       const int* __restrict__ meta_a, const int* __restrict__ meta_c,
                       const float* __restrict__ emb_a, const float* __restrict__ emb_c,
                       const float* __restrict__ W1, const float* __restrict__ b1,
                       const float* __restrict__ W2,
                       float* __restrict__ c_out, int* __restrict__ len_out)
{
  __shared__ int s_bad;
  __shared__ float q_sh[32][128];
  __shared__ float hid[32][64];
  const int tid = threadIdx.x;
  if (tid == 0) s_bad = 0;
  __syncthreads();

  if (tid < 32){
    const unsigned char* m8 = (const unsigned char*)mask;
    int cnt = 0, seen0 = 0, bad = 0;
    for (int t = 0; t < TT; ++t){
      unsigned char v = m8[tid * TT + t];
      if (v > 1) bad = 1;
      if (v){ if (seen0) bad = 1; cnt++; } else seen0 = 1;
    }
    if (tid == 0 && cnt != TT) bad = 1;
    if (bad) atomicAdd(&s_bad, 1);
    len_out[tid] = cnt;
  }
  {
    int b = tid >> 3, p = tid & 7;
    int a = meta_a[b], c = meta_c[b];
    for (int i = 0; i < 16; ++i){
      int qi = p * 16 + i;
      q_sh[b][qi] = (qi < 64) ? emb_a[a * 64 + qi] : emb_c[c * 64 + (qi - 64)];
    }
  }
  __syncthreads();
  if (s_bad){
    if (tid < 32){
      const int* m32 = (const int*)mask;
      int cnt = 0;
      for (int t = 0; t < TT; ++t) if (m32[tid * TT + t]) cnt++;
      len_out[tid] = cnt;
    }
  }
  {
    int b = tid >> 3, kg = tid & 7;
    for (int k8 = 0; k8 < 8; ++k8){
      int k = kg * 8 + k8;
      float s = b1[k];
      for (int i = 0; i < 128; ++i) s += q_sh[b][i] * W1[i * 64 + k];
      hid[b][k] = tanhf(s);
    }
  }
  __syncthreads();
  if (tid < 32){
    float lg[8]; float mx = -1e30f;
    for (int n = 0; n < 8; ++n){
      float s = 0.f;
      for (int k = 0; k < 64; ++k) s += hid[tid][k] * W2[k * 8 + n];
      lg[n] = s; mx = fmaxf(mx, s);
    }
    float den = 0.f;
    for (int n = 0; n < 8; ++n){ lg[n] = expf(lg[n] - mx); den += lg[n]; }
    for (int n = 0; n < 8; ++n) c_out[tid * 8 + n] = lg[n] / den;
  }
}

// ---------------------------------------------------------------------------
__global__ void k_xbf(const float* __restrict__ x, __bf16* __restrict__ xb)
{
  int i = blockIdx.x * 256 + threadIdx.x;
  if (i >= 524288) return;
  f32x4 a = *(const f32x4*)(x + (size_t)i * 8);
  f32x4 b = *(const f32x4*)(x + (size_t)i * 8 + 4);
  bf16x8 o;
  #pragma unroll
  for (int j = 0; j < 4; ++j){ o[j] = f2bf(a[j]); o[4 + j] = f2bf(b[j]); }
  *(bf16x8*)(xb + (size_t)i * 8) = o;
}

// ---------------------------------------------------------------------------
__global__ void k_whhp(const float* __restrict__ whh_f, const float* __restrict__ whh_r,
                       __bf16* __restrict__ outp)
{
  int idx = blockIdx.x * 256 + threadIdx.x;
  int lane = idx & 63; int grp = idx >> 6;
  int n  = grp & 7;  grp >>= 3;
  int kt = grp & 3;  grp >>= 2;
  int wv = grp & 3;  grp >>= 2;
  int wg = grp & 127; int dir = (grp >> 7) & 1;
  int col = lane & 15, quad = lane >> 4;
  int gate = col >> 2, jj = col & 3;
  int g = gate * 512 + wg * 4 + jj;
  int k = (wv * 4 + kt) * 32 + quad * 8;
  const float* Wb = dir ? whh_r : whh_f;
  const float* s = Wb + ((size_t)n * 2048 + g) * 512 + k;
  f32x4 a = *(const f32x4*)s, b = *(const f32x4*)(s + 4);
  bf16x8 o;
  #pragma unroll
  for (int j = 0; j < 4; ++j){ o[j] = f2bf(a[j]); o[4 + j] = f2bf(b[j]); }
  *(bf16x8*)(outp + (size_t)idx * 8) = o;
}

// ---------------------------------------------------------------------------
__global__ void k_bias(const float* __restrict__ b_f, const float* __restrict__ b_r,
                       const float* __restrict__ cb, float* __restrict__ bm)
{
  int idx = blockIdx.x * 256 + threadIdx.x;
  int dir = idx >> 16; int b = (idx >> 11) & 31; int g = idx & 2047;
  const float* bb = dir ? b_r : b_f;
  float s = 0.f;
  #pragma unroll
  for (int n = 0; n < 8; ++n) s += cb[b * 8 + n] * bb[n * 2048 + g];
  bm[idx] = s;
}

// ---------------------------------------------------------------------------
__global__ void k_mixwih(const float* __restrict__ Wb, const float* __restrict__ cb,
                         __bf16* __restrict__ wmix)
{
  __shared__ float cs[256];
  int tid = threadIdx.x;
  cs[tid] = cb[tid];
  __syncthreads();
  int idx = blockIdx.x * 256 + tid;
  int g = idx >> 6, k8 = idx & 63;
  float src[8][8];
  #pragma unroll
  for (int n = 0; n < 8; ++n){
    const float* p = Wb + ((size_t)n * 2048 + g) * 512 + k8 * 8;
    f32x4 lo = *(const f32x4*)p, hi = *(const f32x4*)(p + 4);
    #pragma unroll
    for (int j = 0; j < 4; ++j){ src[n][j] = lo[j]; src[n][4 + j] = hi[j]; }
  }
  for (int b = 0; b < 32; ++b){
    float acc[8] = {0,0,0,0,0,0,0,0};
    #pragma unroll
    for (int n = 0; n < 8; ++n){
      float cn = cs[b * 8 + n];
      #pragma unroll
      for (int j = 0; j < 8; ++j) acc[j] += cn * src[n][j];
    }
    bf16x8 o;
    #pragma unroll
    for (int j = 0; j < 8; ++j) o[j] = f2bf(acc[j]);
    *(bf16x8*)(wmix + ((size_t)b * 2048 + g) * 512 + k8 * 8) = o;
  }
}

// ---------------------------------------------------------------------------
__global__ __launch_bounds__(256) void k_gemm(const __bf16* __restrict__ xb,
                                              const __bf16* __restrict__ wmix,
                                              float* __restrict__ xp)
{
  __shared__ __bf16 As[128][72];
  __shared__ __bf16 Bs[128][72];
  const int tid = threadIdx.x, lane = tid & 63, wv = tid >> 6;
  const int quad = lane >> 4, c16 = lane & 15;
  const int wm_ = wv >> 1, wn_ = wv & 1;
  const int b = blockIdx.x >> 5, tile = blockIdx.x & 31;
  const int m0 = (tile >> 4) * 128, n0 = (tile & 15) * 128;
  const __bf16* Ap = xb + (size_t)b * TT * 512;
  const __bf16* Bp = wmix + (size_t)b * 2048 * 512;
  float* Cp = xp + (size_t)b * TT * 2048;

  f32x4 acc[4][4];
  #pragma unroll
  for (int i = 0; i < 4; ++i)
    #pragma unroll
    for (int j = 0; j < 4; ++j) acc[i][j] = (f32x4){0,0,0,0};

  for (int k0 = 0; k0 < 512; k0 += 64){
    __syncthreads();
    #pragma unroll
    for (int it = 0; it < 4; ++it){
      int r = it * 32 + (tid >> 3), c = (tid & 7) * 8;
      *(bf16x8*)&As[r][c] = *(const bf16x8*)(Ap + (size_t)(m0 + r) * 512 + k0 + c);
      *(bf16x8*)&Bs[r][c] = *(const bf16x8*)(Bp + (size_t)(n0 + r) * 512 + k0 + c);
    }
    __syncthreads();
    #pragma unroll
    for (int kt = 0; kt < 2; ++kt){
      bf16x8 af[4], bfr[4];
      #pragma unroll
      for (int i = 0; i < 4; ++i){
        af[i]  = *(const bf16x8*)&As[wm_ * 64 + i * 16 + c16][kt * 32 + quad * 8];
        bfr[i] = *(const bf16x8*)&Bs[wn_ * 64 + i * 16 + c16][kt * 32 + quad * 8];
      }
      #pragma unroll
      for (int i = 0; i < 4; ++i)
        #pragma unroll
        for (int j = 0; j < 4; ++j)
          acc[i][j] = __builtin_amdgcn_mfma_f32_16x16x32_bf16(af[i], bfr[j], acc[i][j], 0, 0, 0);
    }
  }
  #pragma unroll
  for (int i = 0; i < 4; ++i)
    #pragma unroll
    for (int j = 0; j < 4; ++j){
      int colg = n0 + wn_ * 64 + j * 16 + c16;
      #pragma unroll
      for (int r = 0; r < 4; ++r){
        int row = m0 + wm_ * 64 + i * 16 + quad * 4 + r;
        Cp[(size_t)row * 2048 + colg] = acc[i][j][r];
      }
    }
}

// ---------------------------------------------------------------------------
// k_recur R5. h record buffer: u32x4 hrec[2 dir][2 buf][32 sample][128 wg],
//   record = {h01, h23 (4 bf16 = channels wg*4..wg*4+3), tag, 0}.
// Protocol: buf[p&1] with tag==p is the h INPUT of step p. Block wg writes
//   tag 0 records into buf0 at start, and tag t+1 into buf[(t+1)&1] at the
//   end of step t. Readers poll their fragment records until tag==t.
// Safety: writer reaches "store tag t+2 into buf[t&1]" only after observing
//   all tags t+1, which requires every block to have passed step-t S3 (reads
//   complete, vmcnt-tied before MFMA). Records are 2-step periodic ->
//   equality poll has no false positives. Same transitive proof as R4 flags.
// wg is XCD-swizzled (xproj/out 64B-line locality, kept from R4).
// ---------------------------------------------------------------------------
__global__ __launch_bounds__(256, 1) void k_recur(
    const __bf16* __restrict__ whhp,
    const float*  __restrict__ xproj,   // [2][32][256][2048]
    const float*  __restrict__ biasm,   // [2][32][2048]
    const float*  __restrict__ cb,      // [32][8]
    const int*    __restrict__ lens,    // [32]
    u32x4* hrec,                        // [2][2][32][128]
    float* __restrict__ out)            // [32][256][1024]
{
  const int tid = threadIdx.x, lane = tid & 63, wv = tid >> 6;
  const int quad = lane >> 4, c16 = lane & 15;
  const int bid = blockIdx.x, dir = bid >> 7;
  const int b7 = bid & 127;
  const int wg = ((b7 & 7) << 4) | (b7 >> 3);   // XCD-aware swizzle
  const int hidx0 = wg * 4;

  // basis-weight B fragments -> registers (logical-wg indexed)
  bf16x8 bfrag[4][8];
  {
    const __bf16* base = whhp + (size_t)((dir * 128 + wg) * 4 + wv) * 4 * (8 * 512);
    #pragma unroll
    for (int kt = 0; kt < 4; ++kt)
      #pragma unroll
      for (int n = 0; n < 8; ++n)
        bfrag[kt][n] = *(const bf16x8*)(base + (size_t)(kt * 8 + n) * 512 + lane * 8);
  }
  f32x4 ccv[2][8];
  #pragma unroll
  for (int mt = 0; mt < 2; ++mt)
    #pragma unroll
    for (int n = 0; n < 8; ++n){
      f32x4 v;
      #pragma unroll
      for (int r = 0; r < 4; ++r) v[r] = cb[(mt * 16 + quad * 4 + r) * 8 + n];
      ccv[mt][n] = v;
    }

  const int bb_ = tid >> 2, jj_ = tid & 3;
  float bias_g[4] = {0, 0, 0, 0};
  int mylen = 0;
  float cstate = 0.f;
  if (tid < 128){
    #pragma unroll
    for (int g = 0; g < 4; ++g)
      bias_g[g] = biasm[(size_t)(dir * 32 + bb_) * 2048 + g * 512 + hidx0 + jj_];
    mylen = lens[bb_];
  }

  __shared__ float red[4][2][64][4];
  __shared__ float xg[32][4][4];
  __shared__ float outst[32][4];
  __shared__ __bf16 hbst[32][4];

  u32x4* hb0 = hrec + (size_t)(dir * 2 + 0) * 32 * 128;
  u32x4* hb1 = hrec + (size_t)(dir * 2 + 1) * 32 * 128;

  // init: wave 3 publishes zero-records with tag 0 into buf0 (input step 0)
  if (tid >= 192 && tid < 224){
    int s = tid - 192;
    u32x4 z = {0u, 0u, 0u, 0u};
    st_b128_coh(hb0 + s * 128 + wg, z);
  }

  // prefetch xproj for step 0 (normal cached load; waves 0-1)
  f32x4 pf = {0, 0, 0, 0};
  const int b_pf = tid >> 2, g_pf = tid & 3;
  if (tid < 128){
    int to0 = dir ? (TT - 1) : 0;
    pf = *(const f32x4*)(xproj + ((size_t)(dir * 32 + b_pf) * TT + to0) * 2048
                         + g_pf * 512 + hidx0);
  }

  // per-lane record indices for the 8 fragment pairs (mt*4+kt)
  int ridx[8];
  #pragma unroll
  for (int mt = 0; mt < 2; ++mt)
    #pragma unroll
    for (int kt = 0; kt < 4; ++kt)
      ridx[mt * 4 + kt] = (mt * 16 + c16) * 128 + (wv * 4 + kt) * 8 + quad * 2;

  for (int t = 0; t < TT; ++t){
    const int to = dir ? (TT - 1 - t) : t;
    const u32x4* hb = (t & 1) ? hb1 : hb0;
    const unsigned tgt = (unsigned)t;

    // ---- poll-load the needed h records until all 16 tags == t ----
    u32x4 r0[8], r1[8];
    while (true){
      #pragma unroll
      for (int p = 0; p < 8; ++p){
        r0[p] = ld_b128_coh(hb + ridx[p]);
        r1[p] = ld_b128_coh(hb + ridx[p] + 1);
      }
      asm volatile("s_waitcnt vmcnt(0)"
                   : "+v"(r0[0]), "+v"(r0[1]), "+v"(r0[2]), "+v"(r0[3]),
                     "+v"(r0[4]), "+v"(r0[5]), "+v"(r0[6]), "+v"(r0[7]),
                     "+v"(r1[0]), "+v"(r1[1]), "+v"(r1[2]), "+v"(r1[3]),
                     "+v"(r1[4]), "+v"(r1[5]), "+v"(r1[6]), "+v"(r1[7])
                   :: "memory");
      unsigned bad = 0;
      #pragma unroll
      for (int p = 0; p < 8; ++p)
        bad |= (r0[p][2] ^ tgt) | (r1[p][2] ^ tgt);
      if (__all((int)(bad == 0u))) break;
    }
    bf16x8 af[2][4];
    #pragma unroll
    for (int p = 0; p < 8; ++p){
      u32x4 w = {r0[p][0], r0[p][1], r1[p][0], r1[p][1]};
      af[p >> 2][p & 3] = __builtin_bit_cast(bf16x8, w);
    }

    f32x4 acc[8][2];
    #pragma unroll
    for (int n = 0; n < 8; ++n){ acc[n][0] = (f32x4){0,0,0,0}; acc[n][1] = (f32x4){0,0,0,0}; }
    #pragma unroll
    for (int kt = 0; kt < 4; ++kt)
      #pragma unroll
      for (int n = 0; n < 8; ++n){
        acc[n][0] = __builtin_amdgcn_mfma_f32_16x16x32_bf16(af[0][kt], bfrag[kt][n], acc[n][0], 0, 0, 0);
        acc[n][1] = __builtin_amdgcn_mfma_f32_16x16x32_bf16(af[1][kt], bfrag[kt][n], acc[n][1], 0, 0, 0);
      }
    f32x4 mix0 = {0,0,0,0}, mix1 = {0,0,0,0};
    #pragma unroll
    for (int n = 0; n < 8; ++n){
      mix0 += ccv[0][n] * acc[n][0];
      mix1 += ccv[1][n] * acc[n][1];
    }
    *(f32x4*)&red[wv][0][lane][0] = mix0;
    *(f32x4*)&red[wv][1][lane][0] = mix1;
    if (tid < 128)
      *(f32x4*)&xg[b_pf][g_pf][0] = pf;
    __syncthreads();     // S2

    if (tid < 128){
      const int r = bb_ & 15, mt = bb_ >> 4, rg = r & 3, qp = r >> 2;
      float gv[4];
      #pragma unroll
      for (int g = 0; g < 4; ++g){
        int li = qp * 16 + g * 4 + jj_;
        float s = red[0][mt][li][rg] + red[1][mt][li][rg]
                + red[2][mt][li][rg] + red[3][mt][li][rg];
        gv[g] = s + xg[bb_][g][jj_] + bias_g[g];
      }
      float i_ = sigm(gv[0]);
      float f_ = sigm(gv[1]);
      float g_ = tanh_(gv[2]);
      float o_ = sigm(gv[3]);
      bool valid = (to < mylen);
      float cy = valid ? (f_ * cstate + i_ * g_) : 0.f;
      float hy = valid ? (o_ * tanh_(cy)) : 0.f;
      cstate = cy;
      outst[bb_][jj_] = hy;
      hbst[bb_][jj_] = f2bf(hy);
    }
    __syncthreads();     // S3

    // wave 3: publish tagged h records for step t+1 (fire-and-forget)
    if (tid >= 192 && tid < 224){
      int s = tid - 192;
      union { bf16x4 h; unsigned d[2]; } u;
      u.h = *(bf16x4*)&hbst[s][0];
      u32x4 rec = {u.d[0], u.d[1], (unsigned)(t + 1), 0u};
      u32x4* hn = (t & 1) ? hb0 : hb1;
      st_b128_coh(hn + s * 128 + wg, rec);
    }
    // waves 0-1: prefetch next xproj (cached); wave 2: out store
    if (t < TT - 1 && tid < 128){
      int ton = dir ? (TT - 2 - t) : (t + 1);
      pf = *(const f32x4*)(xproj + ((size_t)(dir * 32 + b_pf) * TT + ton) * 2048
                           + g_pf * 512 + hidx0);
    }
    if (tid >= 128 && tid < 160){
      int s = tid - 128;
      *(f32x4*)(out + ((size_t)s * TT + to) * 1024 + dir * 512 + hidx0)
          = *(f32x4*)&outst[s][0];
    }
  }
}

// ---------------------------------------------------------------------------
extern "C" void kernel_launch(void* const* d_in, const int* in_sizes, int n_in,
                              void* d_out, int out_size, void* d_ws, size_t ws_size,
                              hipStream_t stream)
{
  const float* x      = (const float*)d_in[0];
  const void*  mask   = d_in[1];
  const int*   meta_a = (const int*)d_in[2];
  const int*   meta_c = (const int*)d_in[3];
  const float* emb_a  = (const float*)d_in[4];
  const float* emb_c  = (const float*)d_in[5];
  const float* P_W1   = (const float*)d_in[6];
  const float* P_b1   = (const float*)d_in[7];
  const float* P_W2   = (const float*)d_in[8];
  const float* W_ih   = (const float*)d_in[9];
  const float* W_hh   = (const float*)d_in[10];
  const float* bias_f = (const float*)d_in[11];
  const float* W_ih_r = (const float*)d_in[12];
  const float* W_hh_r = (const float*)d_in[13];
  const float* bias_r = (const float*)d_in[14];
  float* out = (float*)d_out;
  char* ws = (char*)d_ws;

  constexpr size_t OFF_C     = 0;           //   1 KB  c_batch
  constexpr size_t OFF_LEN   = 1024;        //  128 B  lengths
  constexpr size_t OFF_BIAS  = 4096;        //  512 KB mixed biases
  constexpr size_t OFF_H     = 528384;      //  256 KB tagged h records
  constexpr size_t OFF_WHHP  = 790528;      // 33.5 MB basis Whh fragments
  constexpr size_t OFF_XBF   = 34344960;    //  8.4 MB x bf16
  constexpr size_t OFF_WIHM  = 42733568;    //   67 MB mixed Wih (per-dir reuse)
  constexpr size_t OFF_XPROJ = 109842432;   //  134 MB xproj f32 (both dirs)
  constexpr size_t WS_NEED   = 244060160;
  if (ws_size < WS_NEED) return;

  float*   c_b   = (float*)(ws + OFF_C);
  int*     lens  = (int*)(ws + OFF_LEN);
  float*   biasm = (float*)(ws + OFF_BIAS);
  u32x4*   hrec  = (u32x4*)(ws + OFF_H);
  __bf16*  whhp  = (__bf16*)(ws + OFF_WHHP);
  __bf16*  xbf   = (__bf16*)(ws + OFF_XBF);
  __bf16*  wihm  = (__bf16*)(ws + OFF_WIHM);
  float*   xproj = (float*)(ws + OFF_XPROJ);

  k_meta<<<1, 256, 0, stream>>>(mask, meta_a, meta_c, emb_a, emb_c,
                                P_W1, P_b1, P_W2, c_b, lens);
  k_xbf<<<2048, 256, 0, stream>>>(x, xbf);
  k_whhp<<<8192, 256, 0, stream>>>(W_hh, W_hh_r, whhp);
  k_bias<<<512, 256, 0, stream>>>(bias_f, bias_r, c_b, biasm);
  for (int dir = 0; dir < 2; ++dir){
    k_mixwih<<<512, 256, 0, stream>>>(dir ? W_ih_r : W_ih, c_b, wihm);
    k_gemm<<<1024, 256, 0, stream>>>(xbf, wihm,
                                     xproj + (size_t)dir * 32 * TT * 2048);
  }
  k_recur<<<256, 256, 0, stream>>>(whhp, xproj, biasm, c_b, lens, hrec, out);
}